// Round 1
// baseline (14083.209 us; speedup 1.0000x reference)
//
#include <hip/hip_runtime.h>

#define NN 100000
#define NE 1600000
#define NG 64
#define BN_EPS 1e-5f

// ---------------------------------------------------------------- helpers
__device__ __forceinline__ int lower_bound_dev(const int* a, int n, int key) {
  int lo = 0, hi = n;
  while (lo < hi) { int mid = (lo + hi) >> 1; if (a[mid] < key) lo = mid + 1; else hi = mid; }
  return lo;
}

// ---------------------------------------------------------------- aggregation
// agg_in[d] += x[s]; agg_out[s] += x[d]  for each edge (s,d)
template<int DIN>
__global__ __launch_bounds__(256) void k_agg(const float* __restrict__ x,
    const int* __restrict__ src, const int* __restrict__ dst,
    float* __restrict__ agg_in, float* __restrict__ agg_out) {
  constexpr int LPE = DIN / 4;  // lanes per edge (float4 per lane)
  long tid = (long)blockIdx.x * blockDim.x + threadIdx.x;
  long e = tid / LPE;
  if (e >= NE) return;
  int c4 = (int)(tid % LPE) * 4;
  int s = src[e], d = dst[e];
  float4 xs = *(const float4*)(x + (size_t)s * DIN + c4);
  float4 xd = *(const float4*)(x + (size_t)d * DIN + c4);
  float* ai = agg_in + (size_t)d * DIN + c4;
  float* ao = agg_out + (size_t)s * DIN + c4;
  atomicAdd(ai + 0, xs.x); atomicAdd(ai + 1, xs.y);
  atomicAdd(ai + 2, xs.z); atomicAdd(ai + 3, xs.w);
  atomicAdd(ao + 0, xd.x); atomicAdd(ao + 1, xd.y);
  atomicAdd(ao + 2, xd.z); atomicAdd(ao + 3, xd.w);
}

// ---------------------------------------------------------------- fused triple GEMM + ReLU
// out[m][0:128] = relu(A0@W0 + A1@W1 + A2@W2), A* are [NN][DIN], W* are [DIN][128]
template<int DIN>
__global__ __launch_bounds__(256) void k_gemm(
    const float* __restrict__ A0, const float* __restrict__ A1, const float* __restrict__ A2,
    const float* __restrict__ W0, const float* __restrict__ W1, const float* __restrict__ W2,
    float* __restrict__ out) {
  // BM=64, BN=128, BK=32; 256 threads; each thread: 4 rows x 8 cols
  __shared__ float As[32][68];   // [k][m], padded (68*4B % 16B == 0, breaks bank cycles)
  __shared__ float Bs[32][128];  // [k][n]
  const int tid = threadIdx.x;
  const int tx = tid & 15;       // 16 col-groups of 8
  const int ty = tid >> 4;       // 16 row-groups of 4
  const int m0 = blockIdx.x * 64;

  float acc[4][8];
  #pragma unroll
  for (int i = 0; i < 4; ++i)
    #pragma unroll
    for (int j = 0; j < 8; ++j) acc[i][j] = 0.f;

  const float* Alist[3] = {A0, A1, A2};
  const float* Wlist[3] = {W0, W1, W2};

  #pragma unroll
  for (int op = 0; op < 3; ++op) {
    const float* __restrict__ A = Alist[op];
    const float* __restrict__ W = Wlist[op];
    for (int k0 = 0; k0 < DIN; k0 += 32) {
      // stage A tile: 64 rows x 32 k  (512 float4, 2 per thread), transposed into As[k][m]
      #pragma unroll
      for (int l = 0; l < 2; ++l) {
        int idx = tid + l * 256;       // 0..511
        int m = idx >> 3;              // 0..63
        int kq = (idx & 7) * 4;        // 0,4,..,28
        int row = m0 + m;
        float4 v = make_float4(0.f, 0.f, 0.f, 0.f);
        if (row < NN) v = *(const float4*)(A + (size_t)row * DIN + k0 + kq);
        As[kq + 0][m] = v.x; As[kq + 1][m] = v.y;
        As[kq + 2][m] = v.z; As[kq + 3][m] = v.w;
      }
      // stage B tile: 32 k x 128 n (1024 float4, 4 per thread)
      #pragma unroll
      for (int l = 0; l < 4; ++l) {
        int idx = tid + l * 256;       // 0..1023
        int kk = idx >> 5;             // 0..31
        int cq = (idx & 31) * 4;       // 0..124
        *(float4*)&Bs[kk][cq] = *(const float4*)(W + (size_t)(k0 + kk) * 128 + cq);
      }
      __syncthreads();
      #pragma unroll
      for (int k = 0; k < 32; ++k) {
        float a[4], b[8];
        *(float4*)a = *(const float4*)&As[k][ty * 4];
        *(float4*)(b + 0) = *(const float4*)&Bs[k][tx * 8];
        *(float4*)(b + 4) = *(const float4*)&Bs[k][tx * 8 + 4];
        #pragma unroll
        for (int i = 0; i < 4; ++i)
          #pragma unroll
          for (int j = 0; j < 8; ++j)
            acc[i][j] = fmaf(a[i], b[j], acc[i][j]);
      }
      __syncthreads();
    }
  }

  // epilogue: ReLU + store
  #pragma unroll
  for (int i = 0; i < 4; ++i) {
    int row = m0 + ty * 4 + i;
    if (row < NN) {
      float4 v0, v1;
      v0.x = fmaxf(acc[i][0], 0.f); v0.y = fmaxf(acc[i][1], 0.f);
      v0.z = fmaxf(acc[i][2], 0.f); v0.w = fmaxf(acc[i][3], 0.f);
      v1.x = fmaxf(acc[i][4], 0.f); v1.y = fmaxf(acc[i][5], 0.f);
      v1.z = fmaxf(acc[i][6], 0.f); v1.w = fmaxf(acc[i][7], 0.f);
      *(float4*)(out + (size_t)row * 128 + tx * 8) = v0;
      *(float4*)(out + (size_t)row * 128 + tx * 8 + 4) = v1;
    }
  }
}

// ---------------------------------------------------------------- BN stats (sum, sumsq per channel)
__global__ __launch_bounds__(256) void k_stats(const float* __restrict__ h,
                                               double* __restrict__ stats) {
  int c = threadIdx.x & 127;
  int half = threadIdx.x >> 7;  // 0/1
  long r0 = (long)blockIdx.x * 2 + half;
  float s = 0.f, s2 = 0.f;
  for (long r = r0; r < NN; r += (long)gridDim.x * 2) {
    float v = h[r * 128 + c];
    s += v;
    s2 = fmaf(v, v, s2);
  }
  atomicAdd(&stats[c], (double)s);
  atomicAdd(&stats[128 + c], (double)s2);
}

// ---------------------------------------------------------------- BN finalize: mu, rsqrt*gamma, beta
__global__ void k_bn_final(const double* __restrict__ stats, const float* __restrict__ g,
                           const float* __restrict__ b, float* __restrict__ mubn) {
  int c = threadIdx.x;  // 128
  double mu = stats[c] / (double)NN;
  double var = stats[128 + c] / (double)NN - mu * mu;
  float rs = rsqrtf((float)var + BN_EPS);
  mubn[c] = (float)mu;
  mubn[128 + c] = rs * g[c];
  mubn[256 + c] = b[c];
}

// ---------------------------------------------------------------- BN apply (in place)
__global__ __launch_bounds__(256) void k_bn_apply(float* __restrict__ h,
                                                  const float* __restrict__ mubn) {
  size_t i = (size_t)blockIdx.x * blockDim.x + threadIdx.x;
  size_t stride = (size_t)gridDim.x * blockDim.x;
  const size_t total = (size_t)NN * 32;  // float4 count
  for (; i < total; i += stride) {
    int c4 = (int)(i & 31) << 2;
    float4 v = *(float4*)(h + i * 4);
    float4 mu = *(const float4*)(mubn + c4);
    float4 rg = *(const float4*)(mubn + 128 + c4);
    float4 bb = *(const float4*)(mubn + 256 + c4);
    v.x = (v.x - mu.x) * rg.x + bb.x;
    v.y = (v.y - mu.y) * rg.y + bb.y;
    v.z = (v.z - mu.z) * rg.z + bb.z;
    v.w = (v.w - mu.w) * rg.w + bb.w;
    *(float4*)(h + i * 4) = v;
  }
}

// ---------------------------------------------------------------- graph mean-pool (sum stage)
__global__ __launch_bounds__(128) void k_pool(const float* __restrict__ h,
    const int* __restrict__ batch, float* __restrict__ pool) {
  int c = threadIdx.x;  // 128 channels
  int n0 = blockIdx.x * 256;
  if (n0 >= NN) return;
  int nend = n0 + 256; if (nend > NN) nend = NN;
  int cur = batch[n0];
  float run = 0.f;
  for (int n = n0; n < nend; ++n) {
    int g = batch[n];
    if (g != cur) { atomicAdd(&pool[(size_t)cur * 128 + c], run); run = 0.f; cur = g; }
    run += h[(size_t)n * 128 + c];
  }
  atomicAdd(&pool[(size_t)cur * 128 + c], run);
}

// ---------------------------------------------------------------- divide by counts
__global__ __launch_bounds__(128) void k_final(const float* __restrict__ pool,
    const int* __restrict__ batch, float* __restrict__ out) {
  int g = blockIdx.x;   // 64
  int c = threadIdx.x;  // 128
  __shared__ int cnt;
  if (c == 0) {
    int lo = lower_bound_dev(batch, NN, g);
    int hi = lower_bound_dev(batch, NN, g + 1);
    cnt = hi - lo;
  }
  __syncthreads();
  float d = (float)(cnt > 1 ? cnt : 1);
  out[(size_t)g * 128 + c] = pool[(size_t)g * 128 + c] / d;
}

// ---------------------------------------------------------------- launch
extern "C" void kernel_launch(void* const* d_in, const int* in_sizes, int n_in,
                              void* d_out, int out_size, void* d_ws, size_t ws_size,
                              hipStream_t stream) {
  const float* x     = (const float*)d_in[0];
  const int*   ei    = (const int*)d_in[1];
  const int*   batch = (const int*)d_in[2];
  const float* Ws[3] = {(const float*)d_in[3], (const float*)d_in[8],  (const float*)d_in[13]};
  const float* Wi[3] = {(const float*)d_in[4], (const float*)d_in[9],  (const float*)d_in[14]};
  const float* Wo[3] = {(const float*)d_in[5], (const float*)d_in[10], (const float*)d_in[15]};
  const float* gg[3] = {(const float*)d_in[6], (const float*)d_in[11], (const float*)d_in[16]};
  const float* bb[3] = {(const float*)d_in[7], (const float*)d_in[12], (const float*)d_in[17]};
  const int* src = ei;
  const int* dst = ei + NE;

  const size_t HSZ = (size_t)NN * 128;  // elements per full node buffer
  float* h0      = (float*)d_ws;
  float* h1      = h0 + HSZ;
  float* agg_in  = h1 + HSZ;
  float* agg_out = agg_in + HSZ;
  double* stats  = (double*)(agg_out + HSZ);   // 256 doubles
  float* mubn    = (float*)(stats + 256);      // 384 floats
  float* pool    = mubn + 384;                 // 64*128 floats

  const int gemm_grid = (NN + 63) / 64;

  // ---------------- layer 0 (din=64): x -> h0
  hipMemsetAsync(agg_in,  0, (size_t)NN * 64 * 4, stream);
  hipMemsetAsync(agg_out, 0, (size_t)NN * 64 * 4, stream);
  {
    long threads = (long)NE * 16;
    k_agg<64><<<(int)((threads + 255) / 256), 256, 0, stream>>>(x, src, dst, agg_in, agg_out);
    k_gemm<64><<<gemm_grid, 256, 0, stream>>>(x, agg_in, agg_out, Ws[0], Wi[0], Wo[0], h0);
    hipMemsetAsync(stats, 0, 256 * sizeof(double), stream);
    k_stats<<<512, 256, 0, stream>>>(h0, stats);
    k_bn_final<<<1, 128, 0, stream>>>(stats, gg[0], bb[0], mubn);
    k_bn_apply<<<2048, 256, 0, stream>>>(h0, mubn);
  }

  // ---------------- layer 1 (din=128): h0 -> h1
  hipMemsetAsync(agg_in,  0, (size_t)NN * 128 * 4, stream);
  hipMemsetAsync(agg_out, 0, (size_t)NN * 128 * 4, stream);
  {
    long threads = (long)NE * 32;
    k_agg<128><<<(int)((threads + 255) / 256), 256, 0, stream>>>(h0, src, dst, agg_in, agg_out);
    k_gemm<128><<<gemm_grid, 256, 0, stream>>>(h0, agg_in, agg_out, Ws[1], Wi[1], Wo[1], h1);
    hipMemsetAsync(stats, 0, 256 * sizeof(double), stream);
    k_stats<<<512, 256, 0, stream>>>(h1, stats);
    k_bn_final<<<1, 128, 0, stream>>>(stats, gg[1], bb[1], mubn);
    k_bn_apply<<<2048, 256, 0, stream>>>(h1, mubn);
  }

  // ---------------- layer 2 (din=128): h1 -> h0
  hipMemsetAsync(agg_in,  0, (size_t)NN * 128 * 4, stream);
  hipMemsetAsync(agg_out, 0, (size_t)NN * 128 * 4, stream);
  {
    long threads = (long)NE * 32;
    k_agg<128><<<(int)((threads + 255) / 256), 256, 0, stream>>>(h1, src, dst, agg_in, agg_out);
    k_gemm<128><<<gemm_grid, 256, 0, stream>>>(h1, agg_in, agg_out, Ws[2], Wi[2], Wo[2], h0);
    hipMemsetAsync(stats, 0, 256 * sizeof(double), stream);
    k_stats<<<512, 256, 0, stream>>>(h0, stats);
    k_bn_final<<<1, 128, 0, stream>>>(stats, gg[2], bb[2], mubn);
    k_bn_apply<<<2048, 256, 0, stream>>>(h0, mubn);
  }

  // ---------------- global mean pool: h0 -> d_out
  hipMemsetAsync(pool, 0, (size_t)NG * 128 * 4, stream);
  k_pool<<<(NN + 255) / 256, 128, 0, stream>>>(h0, batch, pool);
  k_final<<<NG, 128, 0, stream>>>(pool, batch, (float*)d_out);
}

// Round 2
// 1942.757 us; speedup vs baseline: 7.2491x; 7.2491x over previous
//
#include <hip/hip_runtime.h>

#define NN 100000
#define NE 1600000
#define NG 64
#define BN_EPS 1e-5f

// ---------------------------------------------------------------- helpers
__device__ __forceinline__ int lower_bound_dev(const int* a, int n, int key) {
  int lo = 0, hi = n;
  while (lo < hi) { int mid = (lo + hi) >> 1; if (a[mid] < key) lo = mid + 1; else hi = mid; }
  return lo;
}

// ---------------------------------------------------------------- CSR build
// deg[0..NN)   = in-degree  (edges landing on node, messages x[src] -> dst)
// deg[NN..2NN) = out-degree (messages x[dst] -> src)
__global__ __launch_bounds__(256) void k_hist(const int* __restrict__ src,
    const int* __restrict__ dst, int* __restrict__ deg) {
  int e = blockIdx.x * 256 + threadIdx.x;
  if (e >= NE) return;
  atomicAdd(&deg[dst[e]], 1);
  atomicAdd(&deg[NN + src[e]], 1);
}

// single-block exclusive scan over 2*NN ints -> offs[0..2NN], offs[2NN]=2NE
__global__ __launch_bounds__(1024) void k_scan(const int* __restrict__ deg,
                                               int* __restrict__ offs) {
  __shared__ int part[1024];
  const int T = 1024, total = 2 * NN;
  int t = threadIdx.x;
  int chunk = (total + T - 1) / T;
  int beg = t * chunk, end = beg + chunk; if (end > total) end = total;
  int s = 0;
  for (int i = beg; i < end; ++i) s += deg[i];
  part[t] = s; __syncthreads();
  for (int off = 1; off < T; off <<= 1) {
    int v = (t >= off) ? part[t - off] : 0;
    __syncthreads();
    part[t] += v;
    __syncthreads();
  }
  int run = (t == 0) ? 0 : part[t - 1];
  for (int i = beg; i < end; ++i) { offs[i] = run; run += deg[i]; }
  if (t == T - 1) offs[total] = run;
}

__global__ __launch_bounds__(256) void k_fill(const int* __restrict__ src,
    const int* __restrict__ dst, int* __restrict__ cur, int* __restrict__ nbr) {
  int e = blockIdx.x * 256 + threadIdx.x;
  if (e >= NE) return;
  int s = src[e], d = dst[e];
  int p = atomicAdd(&cur[d], 1);      nbr[p] = s;  // in-list of d holds s
  int q = atomicAdd(&cur[NN + s], 1); nbr[q] = d;  // out-list of s holds d
}

// ---------------------------------------------------------------- gather aggregation
// group g in [0,2NN): g<NN -> agg_in[g] = sum x[nbr], else agg_out[g-NN]
template<int DIN>
__global__ __launch_bounds__(256) void k_gather(const float* __restrict__ x,
    const int* __restrict__ offs, const int* __restrict__ nbr,
    float* __restrict__ agg_in, float* __restrict__ agg_out) {
  constexpr int GW = DIN / 4;              // lanes per group (float4 each)
  constexpr int GPB = 256 / GW;            // groups per block
  int tid = threadIdx.x;
  int g = blockIdx.x * GPB + tid / GW;
  if (g >= 2 * NN) return;
  int c4 = (tid % GW) * 4;
  int beg = offs[g], end = offs[g + 1];
  float4 acc = make_float4(0.f, 0.f, 0.f, 0.f);
  int k = beg;
  for (; k + 4 <= end; k += 4) {
    int n0 = nbr[k], n1 = nbr[k + 1], n2 = nbr[k + 2], n3 = nbr[k + 3];
    float4 v0 = *(const float4*)(x + (size_t)n0 * DIN + c4);
    float4 v1 = *(const float4*)(x + (size_t)n1 * DIN + c4);
    float4 v2 = *(const float4*)(x + (size_t)n2 * DIN + c4);
    float4 v3 = *(const float4*)(x + (size_t)n3 * DIN + c4);
    acc.x += v0.x + v1.x + v2.x + v3.x;
    acc.y += v0.y + v1.y + v2.y + v3.y;
    acc.z += v0.z + v1.z + v2.z + v3.z;
    acc.w += v0.w + v1.w + v2.w + v3.w;
  }
  for (; k < end; ++k) {
    float4 v = *(const float4*)(x + (size_t)nbr[k] * DIN + c4);
    acc.x += v.x; acc.y += v.y; acc.z += v.z; acc.w += v.w;
  }
  float* out = (g < NN) ? (agg_in + (size_t)g * DIN) : (agg_out + (size_t)(g - NN) * DIN);
  *(float4*)(out + c4) = acc;
}

// ---------------------------------------------------------------- fused triple GEMM + ReLU
// out[m][0:128] = relu(A0@W0 + A1@W1 + A2@W2), A* are [NN][DIN], W* are [DIN][128]
template<int DIN>
__global__ __launch_bounds__(256) void k_gemm(
    const float* __restrict__ A0, const float* __restrict__ A1, const float* __restrict__ A2,
    const float* __restrict__ W0, const float* __restrict__ W1, const float* __restrict__ W2,
    float* __restrict__ out) {
  __shared__ float As[32][68];
  __shared__ float Bs[32][128];
  const int tid = threadIdx.x;
  const int tx = tid & 15;
  const int ty = tid >> 4;
  const int m0 = blockIdx.x * 64;

  float acc[4][8];
  #pragma unroll
  for (int i = 0; i < 4; ++i)
    #pragma unroll
    for (int j = 0; j < 8; ++j) acc[i][j] = 0.f;

  const float* Alist[3] = {A0, A1, A2};
  const float* Wlist[3] = {W0, W1, W2};

  #pragma unroll
  for (int op = 0; op < 3; ++op) {
    const float* __restrict__ A = Alist[op];
    const float* __restrict__ W = Wlist[op];
    for (int k0 = 0; k0 < DIN; k0 += 32) {
      #pragma unroll
      for (int l = 0; l < 2; ++l) {
        int idx = tid + l * 256;
        int m = idx >> 3;
        int kq = (idx & 7) * 4;
        int row = m0 + m;
        float4 v = make_float4(0.f, 0.f, 0.f, 0.f);
        if (row < NN) v = *(const float4*)(A + (size_t)row * DIN + k0 + kq);
        As[kq + 0][m] = v.x; As[kq + 1][m] = v.y;
        As[kq + 2][m] = v.z; As[kq + 3][m] = v.w;
      }
      #pragma unroll
      for (int l = 0; l < 4; ++l) {
        int idx = tid + l * 256;
        int kk = idx >> 5;
        int cq = (idx & 31) * 4;
        *(float4*)&Bs[kk][cq] = *(const float4*)(W + (size_t)(k0 + kk) * 128 + cq);
      }
      __syncthreads();
      #pragma unroll
      for (int k = 0; k < 32; ++k) {
        float a[4], b[8];
        *(float4*)a = *(const float4*)&As[k][ty * 4];
        *(float4*)(b + 0) = *(const float4*)&Bs[k][tx * 8];
        *(float4*)(b + 4) = *(const float4*)&Bs[k][tx * 8 + 4];
        #pragma unroll
        for (int i = 0; i < 4; ++i)
          #pragma unroll
          for (int j = 0; j < 8; ++j)
            acc[i][j] = fmaf(a[i], b[j], acc[i][j]);
      }
      __syncthreads();
    }
  }

  #pragma unroll
  for (int i = 0; i < 4; ++i) {
    int row = m0 + ty * 4 + i;
    if (row < NN) {
      float4 v0, v1;
      v0.x = fmaxf(acc[i][0], 0.f); v0.y = fmaxf(acc[i][1], 0.f);
      v0.z = fmaxf(acc[i][2], 0.f); v0.w = fmaxf(acc[i][3], 0.f);
      v1.x = fmaxf(acc[i][4], 0.f); v1.y = fmaxf(acc[i][5], 0.f);
      v1.z = fmaxf(acc[i][6], 0.f); v1.w = fmaxf(acc[i][7], 0.f);
      *(float4*)(out + (size_t)row * 128 + tx * 8) = v0;
      *(float4*)(out + (size_t)row * 128 + tx * 8 + 4) = v1;
    }
  }
}

// ---------------------------------------------------------------- BN stats (sum, sumsq per channel)
__global__ __launch_bounds__(256) void k_stats(const float* __restrict__ h,
                                               double* __restrict__ stats) {
  int c = threadIdx.x & 127;
  int half = threadIdx.x >> 7;
  long r0 = (long)blockIdx.x * 2 + half;
  float s = 0.f, s2 = 0.f;
  for (long r = r0; r < NN; r += (long)gridDim.x * 2) {
    float v = h[r * 128 + c];
    s += v;
    s2 = fmaf(v, v, s2);
  }
  atomicAdd(&stats[c], (double)s);
  atomicAdd(&stats[128 + c], (double)s2);
}

__global__ void k_bn_final(const double* __restrict__ stats, const float* __restrict__ g,
                           const float* __restrict__ b, float* __restrict__ mubn) {
  int c = threadIdx.x;
  double mu = stats[c] / (double)NN;
  double var = stats[128 + c] / (double)NN - mu * mu;
  float rs = rsqrtf((float)var + BN_EPS);
  mubn[c] = (float)mu;
  mubn[128 + c] = rs * g[c];
  mubn[256 + c] = b[c];
}

__global__ __launch_bounds__(256) void k_bn_apply(float* __restrict__ h,
                                                  const float* __restrict__ mubn) {
  size_t i = (size_t)blockIdx.x * blockDim.x + threadIdx.x;
  size_t stride = (size_t)gridDim.x * blockDim.x;
  const size_t total = (size_t)NN * 32;
  for (; i < total; i += stride) {
    int c4 = (int)(i & 31) << 2;
    float4 v = *(float4*)(h + i * 4);
    float4 mu = *(const float4*)(mubn + c4);
    float4 rg = *(const float4*)(mubn + 128 + c4);
    float4 bb = *(const float4*)(mubn + 256 + c4);
    v.x = (v.x - mu.x) * rg.x + bb.x;
    v.y = (v.y - mu.y) * rg.y + bb.y;
    v.z = (v.z - mu.z) * rg.z + bb.z;
    v.w = (v.w - mu.w) * rg.w + bb.w;
    *(float4*)(h + i * 4) = v;
  }
}

// ---------------------------------------------------------------- graph mean-pool
__global__ __launch_bounds__(128) void k_pool(const float* __restrict__ h,
    const int* __restrict__ batch, float* __restrict__ pool) {
  int c = threadIdx.x;
  int n0 = blockIdx.x * 256;
  if (n0 >= NN) return;
  int nend = n0 + 256; if (nend > NN) nend = NN;
  int cur = batch[n0];
  float run = 0.f;
  for (int n = n0; n < nend; ++n) {
    int g = batch[n];
    if (g != cur) { atomicAdd(&pool[(size_t)cur * 128 + c], run); run = 0.f; cur = g; }
    run += h[(size_t)n * 128 + c];
  }
  atomicAdd(&pool[(size_t)cur * 128 + c], run);
}

__global__ __launch_bounds__(128) void k_final(const float* __restrict__ pool,
    const int* __restrict__ batch, float* __restrict__ out) {
  int g = blockIdx.x;
  int c = threadIdx.x;
  __shared__ int cnt;
  if (c == 0) {
    int lo = lower_bound_dev(batch, NN, g);
    int hi = lower_bound_dev(batch, NN, g + 1);
    cnt = hi - lo;
  }
  __syncthreads();
  float d = (float)(cnt > 1 ? cnt : 1);
  out[(size_t)g * 128 + c] = pool[(size_t)g * 128 + c] / d;
}

// ---------------------------------------------------------------- launch
extern "C" void kernel_launch(void* const* d_in, const int* in_sizes, int n_in,
                              void* d_out, int out_size, void* d_ws, size_t ws_size,
                              hipStream_t stream) {
  const float* x     = (const float*)d_in[0];
  const int*   ei    = (const int*)d_in[1];
  const int*   batch = (const int*)d_in[2];
  const float* Ws[3] = {(const float*)d_in[3], (const float*)d_in[8],  (const float*)d_in[13]};
  const float* Wi[3] = {(const float*)d_in[4], (const float*)d_in[9],  (const float*)d_in[14]};
  const float* Wo[3] = {(const float*)d_in[5], (const float*)d_in[10], (const float*)d_in[15]};
  const float* gg[3] = {(const float*)d_in[6], (const float*)d_in[11], (const float*)d_in[16]};
  const float* bb[3] = {(const float*)d_in[7], (const float*)d_in[12], (const float*)d_in[17]};
  const int* src = ei;
  const int* dst = ei + NE;

  const size_t HSZ = (size_t)NN * 128;
  float* h0      = (float*)d_ws;
  float* h1      = h0 + HSZ;
  float* agg_in  = h1 + HSZ;
  float* agg_out = agg_in + HSZ;
  float* fend    = agg_out + HSZ;
  int*   deg     = (int*)fend;                 // 2*NN
  int*   offs    = deg + 2 * NN;               // 2*NN + 1
  int*   cur     = offs + 2 * NN + 1;          // 2*NN
  int*   nbr     = cur + 2 * NN;               // 2*NE
  double* stats  = (double*)(((uintptr_t)(nbr + 2 * NE) + 15) & ~(uintptr_t)15);
  float* mubn    = (float*)(stats + 256);
  float* pool    = mubn + 384;

  const int gemm_grid = (NN + 63) / 64;
  const int egrid = (NE + 255) / 256;

  // ---------------- CSR build (once, reused for all 3 layers)
  hipMemsetAsync(deg, 0, 2 * NN * sizeof(int), stream);
  k_hist<<<egrid, 256, 0, stream>>>(src, dst, deg);
  k_scan<<<1, 1024, 0, stream>>>(deg, offs);
  hipMemcpyAsync(cur, offs, 2 * NN * sizeof(int), hipMemcpyDeviceToDevice, stream);
  k_fill<<<egrid, 256, 0, stream>>>(src, dst, cur, nbr);

  // ---------------- layer 0 (din=64): x -> h0
  {
    k_gather<64><<<(2 * NN + 15) / 16, 256, 0, stream>>>(x, offs, nbr, agg_in, agg_out);
    k_gemm<64><<<gemm_grid, 256, 0, stream>>>(x, agg_in, agg_out, Ws[0], Wi[0], Wo[0], h0);
    hipMemsetAsync(stats, 0, 256 * sizeof(double), stream);
    k_stats<<<512, 256, 0, stream>>>(h0, stats);
    k_bn_final<<<1, 128, 0, stream>>>(stats, gg[0], bb[0], mubn);
    k_bn_apply<<<2048, 256, 0, stream>>>(h0, mubn);
  }

  // ---------------- layer 1 (din=128): h0 -> h1
  {
    k_gather<128><<<(2 * NN + 7) / 8, 256, 0, stream>>>(h0, offs, nbr, agg_in, agg_out);
    k_gemm<128><<<gemm_grid, 256, 0, stream>>>(h0, agg_in, agg_out, Ws[1], Wi[1], Wo[1], h1);
    hipMemsetAsync(stats, 0, 256 * sizeof(double), stream);
    k_stats<<<512, 256, 0, stream>>>(h1, stats);
    k_bn_final<<<1, 128, 0, stream>>>(stats, gg[1], bb[1], mubn);
    k_bn_apply<<<2048, 256, 0, stream>>>(h1, mubn);
  }

  // ---------------- layer 2 (din=128): h1 -> h0
  {
    k_gather<128><<<(2 * NN + 7) / 8, 256, 0, stream>>>(h1, offs, nbr, agg_in, agg_out);
    k_gemm<128><<<gemm_grid, 256, 0, stream>>>(h1, agg_in, agg_out, Ws[2], Wi[2], Wo[2], h0);
    hipMemsetAsync(stats, 0, 256 * sizeof(double), stream);
    k_stats<<<512, 256, 0, stream>>>(h0, stats);
    k_bn_final<<<1, 128, 0, stream>>>(stats, gg[2], bb[2], mubn);
    k_bn_apply<<<2048, 256, 0, stream>>>(h0, mubn);
  }

  // ---------------- global mean pool: h0 -> d_out
  hipMemsetAsync(pool, 0, (size_t)NG * 128 * 4, stream);
  k_pool<<<(NN + 255) / 256, 128, 0, stream>>>(h0, batch, pool);
  k_final<<<NG, 128, 0, stream>>>(pool, batch, (float*)d_out);
}

// Round 3
// 1638.605 us; speedup vs baseline: 8.5946x; 1.1856x over previous
//
#include <hip/hip_runtime.h>

#define NN 100000
#define NE 1600000
#define NG 64
#define BN_EPS 1e-5f

#define TOT (2 * NN)          // scan length
#define SCB 256               // scan blocks
#define CHUNK ((TOT + SCB - 1) / SCB)          // elems per scan block (782)
#define PT ((CHUNK + 255) / 256)               // elems per scan thread (4)
#define STB 256               // stats blocks

// ---------------------------------------------------------------- helpers
__device__ __forceinline__ int lower_bound_dev(const int* a, int n, int key) {
  int lo = 0, hi = n;
  while (lo < hi) { int mid = (lo + hi) >> 1; if (a[mid] < key) lo = mid + 1; else hi = mid; }
  return lo;
}

// ---------------------------------------------------------------- CSR build
__global__ __launch_bounds__(256) void k_hist(const int* __restrict__ src,
    const int* __restrict__ dst, int* __restrict__ deg) {
  int e = blockIdx.x * 256 + threadIdx.x;
  if (e >= NE) return;
  atomicAdd(&deg[dst[e]], 1);        // int atomics: native
  atomicAdd(&deg[NN + src[e]], 1);
}

// multi-block exclusive scan, stage A: per-block sums
__global__ __launch_bounds__(256) void k_scanA(const int* __restrict__ deg,
                                               int* __restrict__ bsum) {
  __shared__ int red[256];
  int t = threadIdx.x;
  int beg = blockIdx.x * CHUNK + t * PT;
  int end = beg + PT;
  int lim = min((blockIdx.x + 1) * CHUNK, TOT);
  if (end > lim) end = lim;
  int s = 0;
  for (int i = beg; i < end && i < TOT; ++i) s += deg[i];
  red[t] = s; __syncthreads();
  for (int off = 128; off > 0; off >>= 1) {
    if (t < off) red[t] += red[t + off];
    __syncthreads();
  }
  if (t == 0) bsum[blockIdx.x] = red[0];
}

// stage B: exclusive scan of SCB block sums (one block)
__global__ __launch_bounds__(SCB) void k_scanB(int* __restrict__ bsum) {
  __shared__ int sc[SCB];
  int t = threadIdx.x;
  sc[t] = bsum[t]; __syncthreads();
  for (int off = 1; off < SCB; off <<= 1) {
    int v = (t >= off) ? sc[t - off] : 0;
    __syncthreads();
    sc[t] += v;
    __syncthreads();
  }
  bsum[t] = (t == 0) ? 0 : sc[t - 1];   // exclusive
}

// stage C: within-block scan + base, write offs
__global__ __launch_bounds__(256) void k_scanC(const int* __restrict__ deg,
    const int* __restrict__ bsum, int* __restrict__ offs) {
  __shared__ int sc[256];
  int t = threadIdx.x;
  int beg = blockIdx.x * CHUNK + t * PT;
  int end = beg + PT;
  int lim = min((blockIdx.x + 1) * CHUNK, TOT);
  if (end > lim) end = lim;
  int s = 0;
  for (int i = beg; i < end && i < TOT; ++i) s += deg[i];
  sc[t] = s; __syncthreads();
  for (int off = 1; off < 256; off <<= 1) {
    int v = (t >= off) ? sc[t - off] : 0;
    __syncthreads();
    sc[t] += v;
    __syncthreads();
  }
  int run = bsum[blockIdx.x] + ((t == 0) ? 0 : sc[t - 1]);
  for (int i = beg; i < end && i < TOT; ++i) {
    offs[i] = run;
    run += deg[i];
    if (i == TOT - 1) offs[TOT] = run;
  }
}

__global__ __launch_bounds__(256) void k_fill(const int* __restrict__ src,
    const int* __restrict__ dst, int* __restrict__ cur, int* __restrict__ nbr) {
  int e = blockIdx.x * 256 + threadIdx.x;
  if (e >= NE) return;
  int s = src[e], d = dst[e];
  int p = atomicAdd(&cur[d], 1);      nbr[p] = s;
  int q = atomicAdd(&cur[NN + s], 1); nbr[q] = d;
}

// ---------------------------------------------------------------- gather aggregation
template<int DIN>
__global__ __launch_bounds__(256) void k_gather(const float* __restrict__ x,
    const int* __restrict__ offs, const int* __restrict__ nbr,
    float* __restrict__ agg_in, float* __restrict__ agg_out) {
  constexpr int GW = DIN / 4;
  constexpr int GPB = 256 / GW;
  int tid = threadIdx.x;
  int g = blockIdx.x * GPB + tid / GW;
  if (g >= 2 * NN) return;
  int c4 = (tid % GW) * 4;
  int beg = offs[g], end = offs[g + 1];
  float4 acc = make_float4(0.f, 0.f, 0.f, 0.f);
  int k = beg;
  for (; k + 4 <= end; k += 4) {
    int n0 = nbr[k], n1 = nbr[k + 1], n2 = nbr[k + 2], n3 = nbr[k + 3];
    float4 v0 = *(const float4*)(x + (size_t)n0 * DIN + c4);
    float4 v1 = *(const float4*)(x + (size_t)n1 * DIN + c4);
    float4 v2 = *(const float4*)(x + (size_t)n2 * DIN + c4);
    float4 v3 = *(const float4*)(x + (size_t)n3 * DIN + c4);
    acc.x += v0.x + v1.x + v2.x + v3.x;
    acc.y += v0.y + v1.y + v2.y + v3.y;
    acc.z += v0.z + v1.z + v2.z + v3.z;
    acc.w += v0.w + v1.w + v2.w + v3.w;
  }
  for (; k < end; ++k) {
    float4 v = *(const float4*)(x + (size_t)nbr[k] * DIN + c4);
    acc.x += v.x; acc.y += v.y; acc.z += v.z; acc.w += v.w;
  }
  float* out = (g < NN) ? (agg_in + (size_t)g * DIN) : (agg_out + (size_t)(g - NN) * DIN);
  *(float4*)(out + c4) = acc;
}

// ---------------------------------------------------------------- fused triple GEMM + ReLU
template<int DIN>
__global__ __launch_bounds__(256) void k_gemm(
    const float* __restrict__ A0, const float* __restrict__ A1, const float* __restrict__ A2,
    const float* __restrict__ W0, const float* __restrict__ W1, const float* __restrict__ W2,
    float* __restrict__ out) {
  __shared__ float As[32][68];
  __shared__ float Bs[32][128];
  const int tid = threadIdx.x;
  const int tx = tid & 15;
  const int ty = tid >> 4;
  const int m0 = blockIdx.x * 64;

  float acc[4][8];
  #pragma unroll
  for (int i = 0; i < 4; ++i)
    #pragma unroll
    for (int j = 0; j < 8; ++j) acc[i][j] = 0.f;

  const float* Alist[3] = {A0, A1, A2};
  const float* Wlist[3] = {W0, W1, W2};

  #pragma unroll
  for (int op = 0; op < 3; ++op) {
    const float* __restrict__ A = Alist[op];
    const float* __restrict__ W = Wlist[op];
    for (int k0 = 0; k0 < DIN; k0 += 32) {
      #pragma unroll
      for (int l = 0; l < 2; ++l) {
        int idx = tid + l * 256;
        int m = idx >> 3;
        int kq = (idx & 7) * 4;
        int row = m0 + m;
        float4 v = make_float4(0.f, 0.f, 0.f, 0.f);
        if (row < NN) v = *(const float4*)(A + (size_t)row * DIN + k0 + kq);
        As[kq + 0][m] = v.x; As[kq + 1][m] = v.y;
        As[kq + 2][m] = v.z; As[kq + 3][m] = v.w;
      }
      #pragma unroll
      for (int l = 0; l < 4; ++l) {
        int idx = tid + l * 256;
        int kk = idx >> 5;
        int cq = (idx & 31) * 4;
        *(float4*)&Bs[kk][cq] = *(const float4*)(W + (size_t)(k0 + kk) * 128 + cq);
      }
      __syncthreads();
      #pragma unroll
      for (int k = 0; k < 32; ++k) {
        float a[4], b[8];
        *(float4*)a = *(const float4*)&As[k][ty * 4];
        *(float4*)(b + 0) = *(const float4*)&Bs[k][tx * 8];
        *(float4*)(b + 4) = *(const float4*)&Bs[k][tx * 8 + 4];
        #pragma unroll
        for (int i = 0; i < 4; ++i)
          #pragma unroll
          for (int j = 0; j < 8; ++j)
            acc[i][j] = fmaf(a[i], b[j], acc[i][j]);
      }
      __syncthreads();
    }
  }

  #pragma unroll
  for (int i = 0; i < 4; ++i) {
    int row = m0 + ty * 4 + i;
    if (row < NN) {
      float4 v0, v1;
      v0.x = fmaxf(acc[i][0], 0.f); v0.y = fmaxf(acc[i][1], 0.f);
      v0.z = fmaxf(acc[i][2], 0.f); v0.w = fmaxf(acc[i][3], 0.f);
      v1.x = fmaxf(acc[i][4], 0.f); v1.y = fmaxf(acc[i][5], 0.f);
      v1.z = fmaxf(acc[i][6], 0.f); v1.w = fmaxf(acc[i][7], 0.f);
      *(float4*)(out + (size_t)row * 128 + tx * 8) = v0;
      *(float4*)(out + (size_t)row * 128 + tx * 8 + 4) = v1;
    }
  }
}

// ---------------------------------------------------------------- BN stats, two-stage, no atomics
// stage A: STB blocks write per-block partial (sum, sumsq) per channel
__global__ __launch_bounds__(256) void k_statsA(const float* __restrict__ h,
                                                float* __restrict__ part) {
  int c = threadIdx.x & 127;
  int half = threadIdx.x >> 7;
  float s = 0.f, s2 = 0.f;
  for (long r = (long)blockIdx.x * 2 + half; r < NN; r += (long)STB * 2) {
    float v = h[r * 128 + c];
    s += v;
    s2 = fmaf(v, v, s2);
  }
  __shared__ float ls[256], ls2[256];
  ls[threadIdx.x] = s; ls2[threadIdx.x] = s2;
  __syncthreads();
  if (half == 0) {
    part[(size_t)blockIdx.x * 256 + c]       = ls[c] + ls[128 + c];
    part[(size_t)blockIdx.x * 256 + 128 + c] = ls2[c] + ls2[128 + c];
  }
}

// stage B: fold STB partials, finalize mu / rsqrt*gamma / beta
__global__ __launch_bounds__(256) void k_bn_final(const float* __restrict__ part,
    const float* __restrict__ g, const float* __restrict__ b, float* __restrict__ mubn) {
  int t = threadIdx.x;  // 256: t<128 -> sum, t>=128 -> sumsq
  float s = 0.f;
  for (int bb = 0; bb < STB; ++bb) s += part[(size_t)bb * 256 + t];
  __shared__ float tot[256];
  tot[t] = s; __syncthreads();
  if (t < 128) {
    float mu = tot[t] / (float)NN;
    float var = tot[128 + t] / (float)NN - mu * mu;
    float rs = rsqrtf(var + BN_EPS);
    mubn[t] = mu;
    mubn[128 + t] = rs * g[t];
    mubn[256 + t] = b[t];
  }
}

// ---------------------------------------------------------------- BN apply (in place)
__global__ __launch_bounds__(256) void k_bn_apply(float* __restrict__ h,
                                                  const float* __restrict__ mubn) {
  size_t i = (size_t)blockIdx.x * blockDim.x + threadIdx.x;
  size_t stride = (size_t)gridDim.x * blockDim.x;
  const size_t total = (size_t)NN * 32;
  for (; i < total; i += stride) {
    int c4 = (int)(i & 31) << 2;
    float4 v = *(float4*)(h + i * 4);
    float4 mu = *(const float4*)(mubn + c4);
    float4 rg = *(const float4*)(mubn + 128 + c4);
    float4 bb = *(const float4*)(mubn + 256 + c4);
    v.x = (v.x - mu.x) * rg.x + bb.x;
    v.y = (v.y - mu.y) * rg.y + bb.y;
    v.z = (v.z - mu.z) * rg.z + bb.z;
    v.w = (v.w - mu.w) * rg.w + bb.w;
    *(float4*)(h + i * 4) = v;
  }
}

// ---------------------------------------------------------------- graph mean-pool
__global__ __launch_bounds__(128) void k_pool(const float* __restrict__ h,
    const int* __restrict__ batch, float* __restrict__ pool) {
  int c = threadIdx.x;
  int n0 = blockIdx.x * 256;
  if (n0 >= NN) return;
  int nend = n0 + 256; if (nend > NN) nend = NN;
  int cur = batch[n0];
  float run = 0.f;
  for (int n = n0; n < nend; ++n) {
    int g = batch[n];
    if (g != cur) { atomicAdd(&pool[(size_t)cur * 128 + c], run); run = 0.f; cur = g; }
    run += h[(size_t)n * 128 + c];
  }
  atomicAdd(&pool[(size_t)cur * 128 + c], run);
}

__global__ __launch_bounds__(128) void k_final(const float* __restrict__ pool,
    const int* __restrict__ batch, float* __restrict__ out) {
  int g = blockIdx.x;
  int c = threadIdx.x;
  __shared__ int cnt;
  if (c == 0) {
    int lo = lower_bound_dev(batch, NN, g);
    int hi = lower_bound_dev(batch, NN, g + 1);
    cnt = hi - lo;
  }
  __syncthreads();
  float d = (float)(cnt > 1 ? cnt : 1);
  out[(size_t)g * 128 + c] = pool[(size_t)g * 128 + c] / d;
}

// ---------------------------------------------------------------- launch
extern "C" void kernel_launch(void* const* d_in, const int* in_sizes, int n_in,
                              void* d_out, int out_size, void* d_ws, size_t ws_size,
                              hipStream_t stream) {
  const float* x     = (const float*)d_in[0];
  const int*   ei    = (const int*)d_in[1];
  const int*   batch = (const int*)d_in[2];
  const float* Ws[3] = {(const float*)d_in[3], (const float*)d_in[8],  (const float*)d_in[13]};
  const float* Wi[3] = {(const float*)d_in[4], (const float*)d_in[9],  (const float*)d_in[14]};
  const float* Wo[3] = {(const float*)d_in[5], (const float*)d_in[10], (const float*)d_in[15]};
  const float* gg[3] = {(const float*)d_in[6], (const float*)d_in[11], (const float*)d_in[16]};
  const float* bb[3] = {(const float*)d_in[7], (const float*)d_in[12], (const float*)d_in[17]};
  const int* src = ei;
  const int* dst = ei + NE;

  const size_t HSZ = (size_t)NN * 128;
  float* h0      = (float*)d_ws;
  float* h1      = h0 + HSZ;
  float* agg_in  = h1 + HSZ;
  float* agg_out = agg_in + HSZ;
  float* fend    = agg_out + HSZ;
  int*   deg     = (int*)fend;                 // 2*NN
  int*   offs    = deg + TOT;                  // 2*NN + 1
  int*   cur     = offs + TOT + 1;             // 2*NN
  int*   bsum    = cur + TOT;                  // SCB
  int*   nbr     = bsum + SCB;                 // 2*NE
  float* part    = (float*)(((uintptr_t)(nbr + 2 * NE) + 15) & ~(uintptr_t)15);  // STB*256
  float* mubn    = part + (size_t)STB * 256;   // 384
  float* pool    = mubn + 384;                 // NG*128

  const int gemm_grid = (NN + 63) / 64;
  const int egrid = (NE + 255) / 256;

  // ---------------- CSR build (once, reused for all 3 layers)
  hipMemsetAsync(deg, 0, TOT * sizeof(int), stream);
  k_hist<<<egrid, 256, 0, stream>>>(src, dst, deg);
  k_scanA<<<SCB, 256, 0, stream>>>(deg, bsum);
  k_scanB<<<1, SCB, 0, stream>>>(bsum);
  k_scanC<<<SCB, 256, 0, stream>>>(deg, bsum, offs);
  hipMemcpyAsync(cur, offs, TOT * sizeof(int), hipMemcpyDeviceToDevice, stream);
  k_fill<<<egrid, 256, 0, stream>>>(src, dst, cur, nbr);

  // ---------------- layer 0 (din=64): x -> h0
  {
    k_gather<64><<<(2 * NN + 15) / 16, 256, 0, stream>>>(x, offs, nbr, agg_in, agg_out);
    k_gemm<64><<<gemm_grid, 256, 0, stream>>>(x, agg_in, agg_out, Ws[0], Wi[0], Wo[0], h0);
    k_statsA<<<STB, 256, 0, stream>>>(h0, part);
    k_bn_final<<<1, 256, 0, stream>>>(part, gg[0], bb[0], mubn);
    k_bn_apply<<<2048, 256, 0, stream>>>(h0, mubn);
  }

  // ---------------- layer 1 (din=128): h0 -> h1
  {
    k_gather<128><<<(2 * NN + 7) / 8, 256, 0, stream>>>(h0, offs, nbr, agg_in, agg_out);
    k_gemm<128><<<gemm_grid, 256, 0, stream>>>(h0, agg_in, agg_out, Ws[1], Wi[1], Wo[1], h1);
    k_statsA<<<STB, 256, 0, stream>>>(h1, part);
    k_bn_final<<<1, 256, 0, stream>>>(part, gg[1], bb[1], mubn);
    k_bn_apply<<<2048, 256, 0, stream>>>(h1, mubn);
  }

  // ---------------- layer 2 (din=128): h1 -> h0
  {
    k_gather<128><<<(2 * NN + 7) / 8, 256, 0, stream>>>(h1, offs, nbr, agg_in, agg_out);
    k_gemm<128><<<gemm_grid, 256, 0, stream>>>(h1, agg_in, agg_out, Ws[2], Wi[2], Wo[2], h0);
    k_statsA<<<STB, 256, 0, stream>>>(h0, part);
    k_bn_final<<<1, 256, 0, stream>>>(part, gg[2], bb[2], mubn);
    k_bn_apply<<<2048, 256, 0, stream>>>(h0, mubn);
  }

  // ---------------- global mean pool: h0 -> d_out
  hipMemsetAsync(pool, 0, (size_t)NG * 128 * 4, stream);
  k_pool<<<(NN + 255) / 256, 128, 0, stream>>>(h0, batch, pool);
  k_final<<<NG, 128, 0, stream>>>(pool, batch, (float*)d_out);
}

// Round 4
// 933.593 us; speedup vs baseline: 15.0850x; 1.7552x over previous
//
#include <hip/hip_runtime.h>

#define NN 100000
#define NE 1600000
#define NG 64
#define BN_EPS 1e-5f

#define TOT (2 * NN)
#define SCB 256
#define CHUNK ((TOT + SCB - 1) / SCB)
#define PT ((CHUNK + 255) / 256)
#define STB 256

typedef __attribute__((ext_vector_type(8))) short bf16x8;
typedef __attribute__((ext_vector_type(8))) unsigned short u16x8;
typedef __attribute__((ext_vector_type(4))) float f32x4;

__device__ __forceinline__ float bf2f(unsigned short u) {
  unsigned int i = (unsigned int)u << 16;
  float f; __builtin_memcpy(&f, &i, 4); return f;
}
__device__ __forceinline__ unsigned short f2bf(float f) {
  unsigned int i; __builtin_memcpy(&i, &f, 4);
  i += 0x7FFFu + ((i >> 16) & 1u);
  return (unsigned short)(i >> 16);
}

__device__ __forceinline__ int lower_bound_dev(const int* a, int n, int key) {
  int lo = 0, hi = n;
  while (lo < hi) { int mid = (lo + hi) >> 1; if (a[mid] < key) lo = mid + 1; else hi = mid; }
  return lo;
}

// ---------------------------------------------------------------- CSR build
__global__ __launch_bounds__(256) void k_hist(const int* __restrict__ src,
    const int* __restrict__ dst, int* __restrict__ deg) {
  int e = blockIdx.x * 256 + threadIdx.x;
  if (e >= NE) return;
  atomicAdd(&deg[dst[e]], 1);
  atomicAdd(&deg[NN + src[e]], 1);
}

__global__ __launch_bounds__(256) void k_scanA(const int* __restrict__ deg,
                                               int* __restrict__ bsum) {
  __shared__ int red[256];
  int t = threadIdx.x;
  int beg = blockIdx.x * CHUNK + t * PT;
  int end = beg + PT;
  int lim = min((blockIdx.x + 1) * CHUNK, TOT);
  if (end > lim) end = lim;
  int s = 0;
  for (int i = beg; i < end && i < TOT; ++i) s += deg[i];
  red[t] = s; __syncthreads();
  for (int off = 128; off > 0; off >>= 1) {
    if (t < off) red[t] += red[t + off];
    __syncthreads();
  }
  if (t == 0) bsum[blockIdx.x] = red[0];
}

__global__ __launch_bounds__(SCB) void k_scanB(int* __restrict__ bsum) {
  __shared__ int sc[SCB];
  int t = threadIdx.x;
  sc[t] = bsum[t]; __syncthreads();
  for (int off = 1; off < SCB; off <<= 1) {
    int v = (t >= off) ? sc[t - off] : 0;
    __syncthreads();
    sc[t] += v;
    __syncthreads();
  }
  bsum[t] = (t == 0) ? 0 : sc[t - 1];
}

__global__ __launch_bounds__(256) void k_scanC(const int* __restrict__ deg,
    const int* __restrict__ bsum, int* __restrict__ offs) {
  __shared__ int sc[256];
  int t = threadIdx.x;
  int beg = blockIdx.x * CHUNK + t * PT;
  int end = beg + PT;
  int lim = min((blockIdx.x + 1) * CHUNK, TOT);
  if (end > lim) end = lim;
  int s = 0;
  for (int i = beg; i < end && i < TOT; ++i) s += deg[i];
  sc[t] = s; __syncthreads();
  for (int off = 1; off < 256; off <<= 1) {
    int v = (t >= off) ? sc[t - off] : 0;
    __syncthreads();
    sc[t] += v;
    __syncthreads();
  }
  int run = bsum[blockIdx.x] + ((t == 0) ? 0 : sc[t - 1]);
  for (int i = beg; i < end && i < TOT; ++i) {
    offs[i] = run;
    run += deg[i];
    if (i == TOT - 1) offs[TOT] = run;
  }
}

__global__ __launch_bounds__(256) void k_fill(const int* __restrict__ src,
    const int* __restrict__ dst, int* __restrict__ cur, int* __restrict__ nbr) {
  int e = blockIdx.x * 256 + threadIdx.x;
  if (e >= NE) return;
  int s = src[e], d = dst[e];
  int p = atomicAdd(&cur[d], 1);      __builtin_nontemporal_store(s, &nbr[p]);
  int q = atomicAdd(&cur[NN + s], 1); __builtin_nontemporal_store(d, &nbr[q]);
}

// ---------------------------------------------------------------- x -> bf16
__global__ __launch_bounds__(256) void k_cvt_x(const float* __restrict__ x,
                                               unsigned short* __restrict__ xb) {
  size_t i = (size_t)blockIdx.x * 256 + threadIdx.x;   // float4 index
  if (i >= (size_t)NN * 16) return;
  float4 v = *(const float4*)(x + i * 4);
  ushort4 o;
  o.x = f2bf(v.x); o.y = f2bf(v.y); o.z = f2bf(v.z); o.w = f2bf(v.w);
  *(ushort4*)(xb + i * 4) = o;
}

// ---------------------------------------------------------------- weight swizzle to MFMA B-frag layout
// frag (op,ks,nt): lane l, elem j  <-  W[ks*32 + (l>>4)*8 + j][nt*16 + (l&15)]
struct WtArgs { const float* W[9]; };
__global__ __launch_bounds__(256) void k_wt(WtArgs a, unsigned short* __restrict__ wt) {
  int t = blockIdx.x * 256 + threadIdx.x;
  if (t >= 15360) return;
  int p, rem, KS;
  if (t < 3072) { p = t >> 10; rem = t & 1023; KS = 2; }
  else { int u = t - 3072; p = 3 + (u >> 11); rem = u & 2047; KS = 4; }
  int ks = rem >> 9;
  int rem2 = rem & 511;
  int nt = rem2 >> 6;
  int lane = rem2 & 63;
  // dst offset: layer base + op*KS*8*512 + (ks*8+nt)*512 + lane*8
  int L = p / 3, op = p - L * 3;
  int lbase = (L == 0) ? 0 : (24576 + (L - 1) * 49152);
  size_t dst = (size_t)lbase + (size_t)op * KS * 4096 + (size_t)(ks * 8 + nt) * 512 + lane * 8;
  const float* W = a.W[p];
  int krow = ks * 32 + (lane >> 4) * 8;
  int col = nt * 16 + (lane & 15);
  #pragma unroll
  for (int j = 0; j < 8; ++j)
    wt[dst + j] = f2bf(W[(size_t)(krow + j) * 128 + col]);
}

__global__ void k_ssid(float* __restrict__ ss) {
  int t = threadIdx.x;  // 128
  ss[t] = 1.f; ss[128 + t] = 0.f;
}

// ---------------------------------------------------------------- gather (bf16 in, bf16 out, end-affine BN)
template<int DIN>
__global__ __launch_bounds__(256) void k_gather(const unsigned short* __restrict__ xb,
    const float* __restrict__ ss, const int* __restrict__ offs, const int* __restrict__ nbr,
    unsigned short* __restrict__ aggi, unsigned short* __restrict__ aggo) {
  constexpr int GW = DIN / 8;           // lanes per group, ushort8 each
  constexpr int GPB = 256 / GW;
  int g = blockIdx.x * GPB + threadIdx.x / GW;
  if (g >= TOT) return;
  int c0 = (threadIdx.x % GW) * 8;
  int beg = offs[g], end = offs[g + 1];
  float acc[8];
  #pragma unroll
  for (int j = 0; j < 8; ++j) acc[j] = 0.f;
  int k = beg;
  for (; k + 4 <= end; k += 4) {
    int n0 = nbr[k], n1 = nbr[k + 1], n2 = nbr[k + 2], n3 = nbr[k + 3];
    u16x8 v0 = *(const u16x8*)(xb + (size_t)n0 * DIN + c0);
    u16x8 v1 = *(const u16x8*)(xb + (size_t)n1 * DIN + c0);
    u16x8 v2 = *(const u16x8*)(xb + (size_t)n2 * DIN + c0);
    u16x8 v3 = *(const u16x8*)(xb + (size_t)n3 * DIN + c0);
    #pragma unroll
    for (int j = 0; j < 8; ++j)
      acc[j] += (bf2f(v0[j]) + bf2f(v1[j])) + (bf2f(v2[j]) + bf2f(v3[j]));
  }
  for (; k < end; ++k) {
    u16x8 v = *(const u16x8*)(xb + (size_t)nbr[k] * DIN + c0);
    #pragma unroll
    for (int j = 0; j < 8; ++j) acc[j] += bf2f(v[j]);
  }
  float cnt = (float)(end - beg);
  unsigned short r[8];
  #pragma unroll
  for (int j = 0; j < 8; ++j)
    r[j] = f2bf(fmaf(acc[j], ss[c0 + j], cnt * ss[128 + c0 + j]));
  unsigned short* o = (g < NN) ? (aggi + (size_t)g * DIN) : (aggo + (size_t)(g - NN) * DIN);
  *(u16x8*)(o + c0) = *(u16x8*)r;
}

// ---------------------------------------------------------------- MFMA GEMM: relu(BN(A0)@W0 + A1@W1 + A2@W2) -> bf16
template<int KD>
__global__ __launch_bounds__(256) void k_gemm(const unsigned short* __restrict__ A0,
    const float* __restrict__ ss, const unsigned short* __restrict__ A1,
    const unsigned short* __restrict__ A2, const unsigned short* __restrict__ wt,
    unsigned short* __restrict__ out) {
  constexpr int KS = KD / 32;
  int tid = threadIdx.x;
  int lane = tid & 63;
  int w = tid >> 6;
  int m0 = blockIdx.x * 64 + w * 16;
  int arow = m0 + (lane & 15);
  int koff = (lane >> 4) * 8;
  f32x4 acc[8];
  #pragma unroll
  for (int nt = 0; nt < 8; ++nt) acc[nt] = (f32x4){0.f, 0.f, 0.f, 0.f};

  const unsigned short* As[3] = {A0, A1, A2};
  #pragma unroll
  for (int op = 0; op < 3; ++op) {
    const unsigned short* __restrict__ A = As[op];
    bf16x8 af[KS];
    if (arow < NN) {
      #pragma unroll
      for (int ks = 0; ks < KS; ++ks)
        af[ks] = *(const bf16x8*)(A + (size_t)arow * KD + ks * 32 + koff);
      if (op == 0) {
        #pragma unroll
        for (int ks = 0; ks < KS; ++ks) {
          union { bf16x8 v; unsigned short u[8]; } tt;
          tt.v = af[ks];
          #pragma unroll
          for (int j = 0; j < 8; ++j) {
            int c = ks * 32 + koff + j;
            tt.u[j] = f2bf(fmaf(bf2f(tt.u[j]), ss[c], ss[128 + c]));
          }
          af[ks] = tt.v;
        }
      }
    } else {
      #pragma unroll
      for (int ks = 0; ks < KS; ++ks) af[ks] = (bf16x8){0,0,0,0,0,0,0,0};
    }
    #pragma unroll
    for (int ks = 0; ks < KS; ++ks) {
      #pragma unroll
      for (int nt = 0; nt < 8; ++nt) {
        bf16x8 bf = *(const bf16x8*)(wt + ((size_t)(op * KS + ks) * 8 + nt) * 512 + lane * 8);
        acc[nt] = __builtin_amdgcn_mfma_f32_16x16x32_bf16(af[ks], bf, acc[nt], 0, 0, 0);
      }
    }
  }

  // epilogue: relu -> bf16, LDS repack (per-wave), coalesced 16B stores
  __shared__ unsigned short lds[4][16][128];
  #pragma unroll
  for (int nt = 0; nt < 8; ++nt)
    #pragma unroll
    for (int r = 0; r < 4; ++r)
      lds[w][(lane >> 4) * 4 + r][nt * 16 + (lane & 15)] = f2bf(fmaxf(acc[nt][r], 0.f));
  #pragma unroll
  for (int it = 0; it < 4; ++it) {
    int rr = (lane >> 4) + it * 4;
    int cc = (lane & 15) * 8;
    int grow = m0 + rr;
    if (grow < NN)
      *(u16x8*)(out + (size_t)grow * 128 + cc) = *(const u16x8*)&lds[w][rr][cc];
  }
}

// ---------------------------------------------------------------- BN stats over bf16 h
__global__ __launch_bounds__(256) void k_statsA(const unsigned short* __restrict__ hb,
                                                float* __restrict__ part) {
  int t = threadIdx.x;
  int q = t & 15;          // channel octet
  int gq = t >> 4;         // row group 0..15
  int c0 = q * 8;
  float s[8], s2[8];
  #pragma unroll
  for (int j = 0; j < 8; ++j) { s[j] = 0.f; s2[j] = 0.f; }
  for (int r = blockIdx.x * 16 + gq; r < NN; r += SCB * 16) {
    u16x8 v = *(const u16x8*)(hb + (size_t)r * 128 + c0);
    #pragma unroll
    for (int j = 0; j < 8; ++j) {
      float f = bf2f(v[j]);
      s[j] += f;
      s2[j] = fmaf(f, f, s2[j]);
    }
  }
  __shared__ float ls[256][8], ls2[256][8];
  #pragma unroll
  for (int j = 0; j < 8; ++j) { ls[t][j] = s[j]; ls2[t][j] = s2[j]; }
  __syncthreads();
  if (t < 128) {
    int qq = t >> 3, jj = t & 7;
    float S = 0.f, S2 = 0.f;
    #pragma unroll
    for (int g = 0; g < 16; ++g) {
      S += ls[g * 16 + qq][jj];
      S2 += ls2[g * 16 + qq][jj];
    }
    part[(size_t)blockIdx.x * 256 + t] = S;
    part[(size_t)blockIdx.x * 256 + 128 + t] = S2;
  }
}

// fold partials -> scale/shift
__global__ __launch_bounds__(256) void k_bn_final(const float* __restrict__ part,
    const float* __restrict__ g, const float* __restrict__ b, float* __restrict__ ss) {
  int t = threadIdx.x;
  float s = 0.f;
  for (int bb = 0; bb < STB; ++bb) s += part[(size_t)bb * 256 + t];
  __shared__ float tot[256];
  tot[t] = s; __syncthreads();
  if (t < 128) {
    float mu = tot[t] / (float)NN;
    float var = tot[128 + t] / (float)NN - mu * mu;
    float rs = rsqrtf(var + BN_EPS);
    float sc = rs * g[t];
    ss[t] = sc;
    ss[128 + t] = b[t] - mu * sc;
  }
}

// ---------------------------------------------------------------- graph mean-pool (raw bf16 sums)
__global__ __launch_bounds__(128) void k_pool(const unsigned short* __restrict__ hb,
    const int* __restrict__ batch, float* __restrict__ pool) {
  int c = threadIdx.x;
  int n0 = blockIdx.x * 256;
  if (n0 >= NN) return;
  int nend = n0 + 256; if (nend > NN) nend = NN;
  int cur = batch[n0];
  float run = 0.f;
  for (int n = n0; n < nend; ++n) {
    int g = batch[n];
    if (g != cur) { atomicAdd(&pool[(size_t)cur * 128 + c], run); run = 0.f; cur = g; }
    run += bf2f(hb[(size_t)n * 128 + c]);
  }
  atomicAdd(&pool[(size_t)cur * 128 + c], run);
}

__global__ __launch_bounds__(128) void k_final(const float* __restrict__ pool,
    const int* __restrict__ batch, const float* __restrict__ ss, float* __restrict__ out) {
  int g = blockIdx.x;
  int c = threadIdx.x;
  __shared__ int cnt;
  if (c == 0) {
    int lo = lower_bound_dev(batch, NN, g);
    int hi = lower_bound_dev(batch, NN, g + 1);
    cnt = hi - lo;
  }
  __syncthreads();
  float d = (float)(cnt > 1 ? cnt : 1);
  out[(size_t)g * 128 + c] = fmaf(pool[(size_t)g * 128 + c] / d, ss[c], ss[128 + c]);
}

// ---------------------------------------------------------------- launch
extern "C" void kernel_launch(void* const* d_in, const int* in_sizes, int n_in,
                              void* d_out, int out_size, void* d_ws, size_t ws_size,
                              hipStream_t stream) {
  const float* x     = (const float*)d_in[0];
  const int*   ei    = (const int*)d_in[1];
  const int*   batch = (const int*)d_in[2];
  const float* gg[3] = {(const float*)d_in[6], (const float*)d_in[11], (const float*)d_in[16]};
  const float* bbv[3]= {(const float*)d_in[7], (const float*)d_in[12], (const float*)d_in[17]};
  const int* src = ei;
  const int* dst = ei + NE;

  uintptr_t p = ((uintptr_t)d_ws + 255) & ~(uintptr_t)255;
  auto alloc = [&](size_t bytes) { uintptr_t r = p; p = (p + bytes + 255) & ~(uintptr_t)255; return r; };

  int* deg   = (int*)alloc(TOT * 4);
  int* offs  = (int*)alloc((TOT + 1) * 4);
  int* cur   = (int*)alloc(TOT * 4);
  int* bsum  = (int*)alloc(SCB * 4);
  int* nbr   = (int*)alloc((size_t)2 * NE * 4);
  unsigned short* xb   = (unsigned short*)alloc((size_t)NN * 64 * 2);
  unsigned short* hb0  = (unsigned short*)alloc((size_t)NN * 128 * 2);
  unsigned short* hb1  = (unsigned short*)alloc((size_t)NN * 128 * 2);
  unsigned short* hb2  = (unsigned short*)alloc((size_t)NN * 128 * 2);
  unsigned short* aggi = (unsigned short*)alloc((size_t)NN * 128 * 2);
  unsigned short* aggo = (unsigned short*)alloc((size_t)NN * 128 * 2);
  unsigned short* wt   = (unsigned short*)alloc(122880 * 2);
  float* part  = (float*)alloc((size_t)STB * 256 * 4);
  float* ss_id = (float*)alloc(256 * 4);
  float* ss0   = (float*)alloc(256 * 4);
  float* ss1   = (float*)alloc(256 * 4);
  float* ss2   = (float*)alloc(256 * 4);
  float* pool  = (float*)alloc((size_t)NG * 128 * 4);

  const int egrid = (NE + 255) / 256;
  const int gemm_grid = (NN + 63) / 64;

  // CSR build
  hipMemsetAsync(deg, 0, TOT * sizeof(int), stream);
  k_hist<<<egrid, 256, 0, stream>>>(src, dst, deg);
  k_scanA<<<SCB, 256, 0, stream>>>(deg, bsum);
  k_scanB<<<1, SCB, 0, stream>>>(bsum);
  k_scanC<<<SCB, 256, 0, stream>>>(deg, bsum, offs);
  hipMemcpyAsync(cur, offs, TOT * sizeof(int), hipMemcpyDeviceToDevice, stream);
  k_fill<<<egrid, 256, 0, stream>>>(src, dst, cur, nbr);

  // conversions
  k_cvt_x<<<(NN * 16 + 255) / 256, 256, 0, stream>>>(x, xb);
  WtArgs wa;
  wa.W[0] = (const float*)d_in[3];  wa.W[1] = (const float*)d_in[4];  wa.W[2] = (const float*)d_in[5];
  wa.W[3] = (const float*)d_in[8];  wa.W[4] = (const float*)d_in[9];  wa.W[5] = (const float*)d_in[10];
  wa.W[6] = (const float*)d_in[13]; wa.W[7] = (const float*)d_in[14]; wa.W[8] = (const float*)d_in[15];
  k_wt<<<60, 256, 0, stream>>>(wa, wt);
  k_ssid<<<1, 128, 0, stream>>>(ss_id);

  // layer 0 (KD=64): xb -> hb0
  k_gather<64><<<(TOT + 31) / 32, 256, 0, stream>>>(xb, ss_id, offs, nbr, aggi, aggo);
  k_gemm<64><<<gemm_grid, 256, 0, stream>>>(xb, ss_id, aggi, aggo, wt + 0, hb0);
  k_statsA<<<STB, 256, 0, stream>>>(hb0, part);
  k_bn_final<<<1, 256, 0, stream>>>(part, gg[0], bbv[0], ss0);

  // layer 1 (KD=128): hb0 -> hb1
  k_gather<128><<<(TOT + 15) / 16, 256, 0, stream>>>(hb0, ss0, offs, nbr, aggi, aggo);
  k_gemm<128><<<gemm_grid, 256, 0, stream>>>(hb0, ss0, aggi, aggo, wt + 24576, hb1);
  k_statsA<<<STB, 256, 0, stream>>>(hb1, part);
  k_bn_final<<<1, 256, 0, stream>>>(part, gg[1], bbv[1], ss1);

  // layer 2 (KD=128): hb1 -> hb2
  k_gather<128><<<(TOT + 15) / 16, 256, 0, stream>>>(hb1, ss1, offs, nbr, aggi, aggo);
  k_gemm<128><<<gemm_grid, 256, 0, stream>>>(hb1, ss1, aggi, aggo, wt + 73728, hb2);
  k_statsA<<<STB, 256, 0, stream>>>(hb2, part);
  k_bn_final<<<1, 256, 0, stream>>>(part, gg[2], bbv[2], ss2);

  // pool
  hipMemsetAsync(pool, 0, (size_t)NG * 128 * 4, stream);
  k_pool<<<(NN + 255) / 256, 128, 0, stream>>>(hb2, batch, pool);
  k_final<<<NG, 128, 0, stream>>>(pool, batch, ss2, (float*)d_out);
}

// Round 5
// 626.100 us; speedup vs baseline: 22.4935x; 1.4911x over previous
//
#include <hip/hip_runtime.h>

#define NN 100000
#define NE 1600000
#define NG 64
#define BN_EPS 1e-5f

#define TOT (2 * NN)
#define STB 256

// bucketed CSR build
#define NB 98                     // buckets of 2048 keys: key >> 11, keys < 200000
#define BCAP 36864                // padded per-bucket capacity (avg 32653, sigma ~180)
#define EPB ((NE + 1023) / 1024)  // edges per phase-1 block (1563)

typedef __attribute__((ext_vector_type(8))) short bf16x8;
typedef __attribute__((ext_vector_type(8))) unsigned short u16x8;
typedef __attribute__((ext_vector_type(4))) float f32x4;

__device__ __forceinline__ float bf2f(unsigned short u) {
  unsigned int i = (unsigned int)u << 16;
  float f; __builtin_memcpy(&f, &i, 4); return f;
}
__device__ __forceinline__ unsigned short f2bf(float f) {
  unsigned int i; __builtin_memcpy(&i, &f, 4);
  i += 0x7FFFu + ((i >> 16) & 1u);
  return (unsigned short)(i >> 16);
}

__device__ __forceinline__ int lower_bound_dev(const int* a, int n, int key) {
  int lo = 0, hi = n;
  while (lo < hi) { int mid = (lo + hi) >> 1; if (a[mid] < key) lo = mid + 1; else hi = mid; }
  return lo;
}

// ---------------------------------------------------------------- CSR phase 1: bucket scatter (write-combined)
// pair stream: for edge (s,d): (key=d, pay=s) and (key=s+NN, pay=d). val = (key&2047)<<17 | pay
__global__ __launch_bounds__(256) void k_p1(const int* __restrict__ src,
    const int* __restrict__ dst, int* __restrict__ gcur, unsigned int* __restrict__ pairs) {
  __shared__ unsigned int lbuf[NB][64];
  __shared__ int lcnt[NB], lbase[NB];
  __shared__ int sc[256];
  int t = threadIdx.x;
  if (t < NB) lcnt[t] = 0;
  __syncthreads();
  int e0 = blockIdx.x * EPB;
  int e1 = min(e0 + EPB, NE);
  for (int e = e0 + t; e < e1; e += 256) {
    int s = src[e], d = dst[e];
    {
      int key = d;
      unsigned int val = ((unsigned int)(key & 2047) << 17) | (unsigned int)s;
      int bk = key >> 11;
      int p = atomicAdd(&lcnt[bk], 1);
      if (p < 64) lbuf[bk][p] = val;
      else { int g = atomicAdd(&gcur[bk], 1); pairs[(size_t)bk * BCAP + g] = val; }
    }
    {
      int key = s + NN;
      unsigned int val = ((unsigned int)(key & 2047) << 17) | (unsigned int)d;
      int bk = key >> 11;
      int p = atomicAdd(&lcnt[bk], 1);
      if (p < 64) lbuf[bk][p] = val;
      else { int g = atomicAdd(&gcur[bk], 1); pairs[(size_t)bk * BCAP + g] = val; }
    }
  }
  __syncthreads();
  if (t < NB) {
    int c = min(lcnt[t], 64);
    lcnt[t] = c;
    lbase[t] = atomicAdd(&gcur[t], c);
  }
  __syncthreads();
  sc[t] = (t < NB) ? lcnt[t] : 0;
  __syncthreads();
  for (int off = 1; off < 256; off <<= 1) {
    int x = (t >= off) ? sc[t - off] : 0;
    __syncthreads();
    sc[t] += x;
    __syncthreads();
  }
  int total = sc[NB - 1];
  for (int idx = t; idx < total; idx += 256) {
    int lo = 0, hi = NB - 1;
    while (lo < hi) { int mid = (lo + hi) >> 1; if (sc[mid] > idx) hi = mid; else lo = mid + 1; }
    int within = idx - ((lo == 0) ? 0 : sc[lo - 1]);
    pairs[(size_t)lo * BCAP + lbase[lo] + within] = lbuf[lo][within];
  }
}

// ---------------------------------------------------------------- CSR phase 1.5: scan 98 bucket counts
__global__ void k_scan98(const int* __restrict__ gcur, int* __restrict__ fbase) {
  __shared__ int sc[128];
  int t = threadIdx.x;
  sc[t] = (t < NB) ? gcur[t] : 0;
  __syncthreads();
  for (int off = 1; off < 128; off <<= 1) {
    int x = (t >= off) ? sc[t - off] : 0;
    __syncthreads();
    sc[t] += x;
    __syncthreads();
  }
  if (t < NB) fbase[t] = (t == 0) ? 0 : sc[t - 1];
  if (t == 0) fbase[NB] = sc[NB - 1];
}

// ---------------------------------------------------------------- CSR phase 2: per-bucket hist/scan/scatter
__global__ __launch_bounds__(256) void k_p2(const unsigned int* __restrict__ pairs,
    const int* __restrict__ gcur, const int* __restrict__ fbase,
    int* __restrict__ offs, int* __restrict__ nbr) {
  int b = blockIdx.x;
  int n = gcur[b];
  int base = fbase[b];
  __shared__ int hist[2048];
  __shared__ int sc[256];
  int t = threadIdx.x;
  #pragma unroll
  for (int j = 0; j < 8; ++j) hist[t * 8 + j] = 0;
  __syncthreads();
  const unsigned int* bp = pairs + (size_t)b * BCAP;
  for (int i = t; i < n; i += 256) atomicAdd(&hist[bp[i] >> 17], 1);
  __syncthreads();
  int v[8]; int tsum = 0;
  #pragma unroll
  for (int j = 0; j < 8; ++j) { v[j] = hist[t * 8 + j]; tsum += v[j]; }
  sc[t] = tsum;
  __syncthreads();
  for (int off = 1; off < 256; off <<= 1) {
    int x = (t >= off) ? sc[t - off] : 0;
    __syncthreads();
    sc[t] += x;
    __syncthreads();
  }
  int run = (t == 0) ? 0 : sc[t - 1];
  #pragma unroll
  for (int j = 0; j < 8; ++j) {
    int key = b * 2048 + t * 8 + j;
    if (key < TOT) offs[key] = base + run;
    hist[t * 8 + j] = run;
    run += v[j];
  }
  if (b == NB - 1 && t == 0) offs[TOT] = base + n;
  __syncthreads();
  for (int i = t; i < n; i += 256) {
    unsigned int u = bp[i];
    int lk = (int)(u >> 17);
    int pos = atomicAdd(&hist[lk], 1);
    nbr[base + pos] = (int)(u & 0x1FFFFu);
  }
}

// ---------------------------------------------------------------- x -> bf16
__global__ __launch_bounds__(256) void k_cvt_x(const float* __restrict__ x,
                                               unsigned short* __restrict__ xb) {
  size_t i = (size_t)blockIdx.x * 256 + threadIdx.x;
  if (i >= (size_t)NN * 16) return;
  float4 v = *(const float4*)(x + i * 4);
  ushort4 o;
  o.x = f2bf(v.x); o.y = f2bf(v.y); o.z = f2bf(v.z); o.w = f2bf(v.w);
  *(ushort4*)(xb + i * 4) = o;
}

// ---------------------------------------------------------------- weight swizzle to MFMA B-frag layout
struct WtArgs { const float* W[9]; };
__global__ __launch_bounds__(256) void k_wt(WtArgs a, unsigned short* __restrict__ wt) {
  int t = blockIdx.x * 256 + threadIdx.x;
  if (t >= 15360) return;
  int p, rem, KS;
  if (t < 3072) { p = t >> 10; rem = t & 1023; KS = 2; }
  else { int u = t - 3072; p = 3 + (u >> 11); rem = u & 2047; KS = 4; }
  int ks = rem >> 9;
  int rem2 = rem & 511;
  int nt = rem2 >> 6;
  int lane = rem2 & 63;
  int L = p / 3, op = p - L * 3;
  int lbase = (L == 0) ? 0 : (24576 + (L - 1) * 49152);
  size_t dst = (size_t)lbase + (size_t)op * KS * 4096 + (size_t)(ks * 8 + nt) * 512 + lane * 8;
  const float* W = a.W[p];
  int krow = ks * 32 + (lane >> 4) * 8;
  int col = nt * 16 + (lane & 15);
  #pragma unroll
  for (int j = 0; j < 8; ++j)
    wt[dst + j] = f2bf(W[(size_t)(krow + j) * 128 + col]);
}

__global__ void k_ssid(float* __restrict__ ss) {
  int t = threadIdx.x;
  ss[t] = 1.f; ss[128 + t] = 0.f;
}

// ---------------------------------------------------------------- gather (bf16 in, bf16 out, end-affine BN)
template<int DIN>
__global__ __launch_bounds__(256) void k_gather(const unsigned short* __restrict__ xb,
    const float* __restrict__ ss, const int* __restrict__ offs, const int* __restrict__ nbr,
    unsigned short* __restrict__ aggi, unsigned short* __restrict__ aggo) {
  constexpr int GW = DIN / 8;
  constexpr int GPB = 256 / GW;
  int g = blockIdx.x * GPB + threadIdx.x / GW;
  if (g >= TOT) return;
  int c0 = (threadIdx.x % GW) * 8;
  int beg = offs[g], end = offs[g + 1];
  float acc[8];
  #pragma unroll
  for (int j = 0; j < 8; ++j) acc[j] = 0.f;
  int k = beg;
  for (; k + 4 <= end; k += 4) {
    int n0 = nbr[k], n1 = nbr[k + 1], n2 = nbr[k + 2], n3 = nbr[k + 3];
    u16x8 v0 = *(const u16x8*)(xb + (size_t)n0 * DIN + c0);
    u16x8 v1 = *(const u16x8*)(xb + (size_t)n1 * DIN + c0);
    u16x8 v2 = *(const u16x8*)(xb + (size_t)n2 * DIN + c0);
    u16x8 v3 = *(const u16x8*)(xb + (size_t)n3 * DIN + c0);
    #pragma unroll
    for (int j = 0; j < 8; ++j)
      acc[j] += (bf2f(v0[j]) + bf2f(v1[j])) + (bf2f(v2[j]) + bf2f(v3[j]));
  }
  for (; k < end; ++k) {
    u16x8 v = *(const u16x8*)(xb + (size_t)nbr[k] * DIN + c0);
    #pragma unroll
    for (int j = 0; j < 8; ++j) acc[j] += bf2f(v[j]);
  }
  float cnt = (float)(end - beg);
  unsigned short r[8];
  #pragma unroll
  for (int j = 0; j < 8; ++j)
    r[j] = f2bf(fmaf(acc[j], ss[c0 + j], cnt * ss[128 + c0 + j]));
  unsigned short* o = (g < NN) ? (aggi + (size_t)g * DIN) : (aggo + (size_t)(g - NN) * DIN);
  *(u16x8*)(o + c0) = *(u16x8*)r;
}

// ---------------------------------------------------------------- MFMA GEMM: relu(BN(A0)@W0 + A1@W1 + A2@W2) -> bf16
template<int KD>
__global__ __launch_bounds__(256) void k_gemm(const unsigned short* __restrict__ A0,
    const float* __restrict__ ss, const unsigned short* __restrict__ A1,
    const unsigned short* __restrict__ A2, const unsigned short* __restrict__ wt,
    unsigned short* __restrict__ out) {
  constexpr int KS = KD / 32;
  int tid = threadIdx.x;
  int lane = tid & 63;
  int w = tid >> 6;
  int m0 = blockIdx.x * 64 + w * 16;
  int arow = m0 + (lane & 15);
  int koff = (lane >> 4) * 8;
  f32x4 acc[8];
  #pragma unroll
  for (int nt = 0; nt < 8; ++nt) acc[nt] = (f32x4){0.f, 0.f, 0.f, 0.f};

  const unsigned short* As[3] = {A0, A1, A2};
  #pragma unroll
  for (int op = 0; op < 3; ++op) {
    const unsigned short* __restrict__ A = As[op];
    bf16x8 af[KS];
    if (arow < NN) {
      #pragma unroll
      for (int ks = 0; ks < KS; ++ks)
        af[ks] = *(const bf16x8*)(A + (size_t)arow * KD + ks * 32 + koff);
      if (op == 0) {
        #pragma unroll
        for (int ks = 0; ks < KS; ++ks) {
          union { bf16x8 v; unsigned short u[8]; } tt;
          tt.v = af[ks];
          #pragma unroll
          for (int j = 0; j < 8; ++j) {
            int c = ks * 32 + koff + j;
            tt.u[j] = f2bf(fmaf(bf2f(tt.u[j]), ss[c], ss[128 + c]));
          }
          af[ks] = tt.v;
        }
      }
    } else {
      #pragma unroll
      for (int ks = 0; ks < KS; ++ks) af[ks] = (bf16x8){0,0,0,0,0,0,0,0};
    }
    #pragma unroll
    for (int ks = 0; ks < KS; ++ks) {
      #pragma unroll
      for (int nt = 0; nt < 8; ++nt) {
        bf16x8 bf = *(const bf16x8*)(wt + ((size_t)(op * KS + ks) * 8 + nt) * 512 + lane * 8);
        acc[nt] = __builtin_amdgcn_mfma_f32_16x16x32_bf16(af[ks], bf, acc[nt], 0, 0, 0);
      }
    }
  }

  __shared__ unsigned short lds[4][16][128];
  #pragma unroll
  for (int nt = 0; nt < 8; ++nt)
    #pragma unroll
    for (int r = 0; r < 4; ++r)
      lds[w][(lane >> 4) * 4 + r][nt * 16 + (lane & 15)] = f2bf(fmaxf(acc[nt][r], 0.f));
  #pragma unroll
  for (int it = 0; it < 4; ++it) {
    int rr = (lane >> 4) + it * 4;
    int cc = (lane & 15) * 8;
    int grow = m0 + rr;
    if (grow < NN)
      *(u16x8*)(out + (size_t)grow * 128 + cc) = *(const u16x8*)&lds[w][rr][cc];
  }
}

// ---------------------------------------------------------------- BN stats over bf16 h
__global__ __launch_bounds__(256) void k_statsA(const unsigned short* __restrict__ hb,
                                                float* __restrict__ part) {
  int t = threadIdx.x;
  int q = t & 15;
  int gq = t >> 4;
  int c0 = q * 8;
  float s[8], s2[8];
  #pragma unroll
  for (int j = 0; j < 8; ++j) { s[j] = 0.f; s2[j] = 0.f; }
  for (int r = blockIdx.x * 16 + gq; r < NN; r += STB * 16) {
    u16x8 v = *(const u16x8*)(hb + (size_t)r * 128 + c0);
    #pragma unroll
    for (int j = 0; j < 8; ++j) {
      float f = bf2f(v[j]);
      s[j] += f;
      s2[j] = fmaf(f, f, s2[j]);
    }
  }
  __shared__ float ls[256][8], ls2[256][8];
  #pragma unroll
  for (int j = 0; j < 8; ++j) { ls[t][j] = s[j]; ls2[t][j] = s2[j]; }
  __syncthreads();
  if (t < 128) {
    int qq = t >> 3, jj = t & 7;
    float S = 0.f, S2 = 0.f;
    #pragma unroll
    for (int g = 0; g < 16; ++g) {
      S += ls[g * 16 + qq][jj];
      S2 += ls2[g * 16 + qq][jj];
    }
    part[(size_t)blockIdx.x * 256 + t] = S;
    part[(size_t)blockIdx.x * 256 + 128 + t] = S2;
  }
}

__global__ __launch_bounds__(256) void k_bn_final(const float* __restrict__ part,
    const float* __restrict__ g, const float* __restrict__ b, float* __restrict__ ss) {
  int t = threadIdx.x;
  float s = 0.f;
  for (int bb = 0; bb < STB; ++bb) s += part[(size_t)bb * 256 + t];
  __shared__ float tot[256];
  tot[t] = s; __syncthreads();
  if (t < 128) {
    float mu = tot[t] / (float)NN;
    float var = tot[128 + t] / (float)NN - mu * mu;
    float rs = rsqrtf(var + BN_EPS);
    float sc = rs * g[t];
    ss[t] = sc;
    ss[128 + t] = b[t] - mu * sc;
  }
}

// ---------------------------------------------------------------- graph mean-pool (raw bf16 sums)
__global__ __launch_bounds__(128) void k_pool(const unsigned short* __restrict__ hb,
    const int* __restrict__ batch, float* __restrict__ pool) {
  int c = threadIdx.x;
  int n0 = blockIdx.x * 256;
  if (n0 >= NN) return;
  int nend = n0 + 256; if (nend > NN) nend = NN;
  int cur = batch[n0];
  float run = 0.f;
  for (int n = n0; n < nend; ++n) {
    int g = batch[n];
    if (g != cur) { atomicAdd(&pool[(size_t)cur * 128 + c], run); run = 0.f; cur = g; }
    run += bf2f(hb[(size_t)n * 128 + c]);
  }
  atomicAdd(&pool[(size_t)cur * 128 + c], run);
}

__global__ __launch_bounds__(128) void k_final(const float* __restrict__ pool,
    const int* __restrict__ batch, const float* __restrict__ ss, float* __restrict__ out) {
  int g = blockIdx.x;
  int c = threadIdx.x;
  __shared__ int cnt;
  if (c == 0) {
    int lo = lower_bound_dev(batch, NN, g);
    int hi = lower_bound_dev(batch, NN, g + 1);
    cnt = hi - lo;
  }
  __syncthreads();
  float d = (float)(cnt > 1 ? cnt : 1);
  out[(size_t)g * 128 + c] = fmaf(pool[(size_t)g * 128 + c] / d, ss[c], ss[128 + c]);
}

// ---------------------------------------------------------------- launch
extern "C" void kernel_launch(void* const* d_in, const int* in_sizes, int n_in,
                              void* d_out, int out_size, void* d_ws, size_t ws_size,
                              hipStream_t stream) {
  const float* x     = (const float*)d_in[0];
  const int*   ei    = (const int*)d_in[1];
  const int*   batch = (const int*)d_in[2];
  const float* gg[3] = {(const float*)d_in[6], (const float*)d_in[11], (const float*)d_in[16]};
  const float* bbv[3]= {(const float*)d_in[7], (const float*)d_in[12], (const float*)d_in[17]};
  const int* src = ei;
  const int* dst = ei + NE;

  uintptr_t p = ((uintptr_t)d_ws + 255) & ~(uintptr_t)255;
  auto alloc = [&](size_t bytes) { uintptr_t r = p; p = (p + bytes + 255) & ~(uintptr_t)255; return r; };

  unsigned int* pairs = (unsigned int*)alloc((size_t)NB * BCAP * 4);
  int* gcur  = (int*)alloc(NB * 4);
  int* fbase = (int*)alloc((NB + 1) * 4);
  int* offs  = (int*)alloc((TOT + 1) * 4);
  int* nbr   = (int*)alloc((size_t)2 * NE * 4);
  unsigned short* xb   = (unsigned short*)alloc((size_t)NN * 64 * 2);
  unsigned short* hb0  = (unsigned short*)alloc((size_t)NN * 128 * 2);
  unsigned short* hb1  = (unsigned short*)alloc((size_t)NN * 128 * 2);
  unsigned short* hb2  = (unsigned short*)alloc((size_t)NN * 128 * 2);
  unsigned short* aggi = (unsigned short*)alloc((size_t)NN * 128 * 2);
  unsigned short* aggo = (unsigned short*)alloc((size_t)NN * 128 * 2);
  unsigned short* wt   = (unsigned short*)alloc(122880 * 2);
  float* part  = (float*)alloc((size_t)STB * 256 * 4);
  float* ss_id = (float*)alloc(256 * 4);
  float* ss0   = (float*)alloc(256 * 4);
  float* ss1   = (float*)alloc(256 * 4);
  float* ss2   = (float*)alloc(256 * 4);
  float* pool  = (float*)alloc((size_t)NG * 128 * 4);

  const int gemm_grid = (NN + 63) / 64;

  // CSR build (bucketed, write-combined)
  hipMemsetAsync(gcur, 0, NB * sizeof(int), stream);
  k_p1<<<1024, 256, 0, stream>>>(src, dst, gcur, pairs);
  k_scan98<<<1, 128, 0, stream>>>(gcur, fbase);
  k_p2<<<NB, 256, 0, stream>>>(pairs, gcur, fbase, offs, nbr);

  // conversions
  k_cvt_x<<<(NN * 16 + 255) / 256, 256, 0, stream>>>(x, xb);
  WtArgs wa;
  wa.W[0] = (const float*)d_in[3];  wa.W[1] = (const float*)d_in[4];  wa.W[2] = (const float*)d_in[5];
  wa.W[3] = (const float*)d_in[8];  wa.W[4] = (const float*)d_in[9];  wa.W[5] = (const float*)d_in[10];
  wa.W[6] = (const float*)d_in[13]; wa.W[7] = (const float*)d_in[14]; wa.W[8] = (const float*)d_in[15];
  k_wt<<<60, 256, 0, stream>>>(wa, wt);
  k_ssid<<<1, 128, 0, stream>>>(ss_id);

  // layer 0 (KD=64): xb -> hb0
  k_gather<64><<<(TOT + 31) / 32, 256, 0, stream>>>(xb, ss_id, offs, nbr, aggi, aggo);
  k_gemm<64><<<gemm_grid, 256, 0, stream>>>(xb, ss_id, aggi, aggo, wt + 0, hb0);
  k_statsA<<<STB, 256, 0, stream>>>(hb0, part);
  k_bn_final<<<1, 256, 0, stream>>>(part, gg[0], bbv[0], ss0);

  // layer 1 (KD=128): hb0 -> hb1
  k_gather<128><<<(TOT + 15) / 16, 256, 0, stream>>>(hb0, ss0, offs, nbr, aggi, aggo);
  k_gemm<128><<<gemm_grid, 256, 0, stream>>>(hb0, ss0, aggi, aggo, wt + 24576, hb1);
  k_statsA<<<STB, 256, 0, stream>>>(hb1, part);
  k_bn_final<<<1, 256, 0, stream>>>(part, gg[1], bbv[1], ss1);

  // layer 2 (KD=128): hb1 -> hb2
  k_gather<128><<<(TOT + 15) / 16, 256, 0, stream>>>(hb1, ss1, offs, nbr, aggi, aggo);
  k_gemm<128><<<gemm_grid, 256, 0, stream>>>(hb1, ss1, aggi, aggo, wt + 73728, hb2);
  k_statsA<<<STB, 256, 0, stream>>>(hb2, part);
  k_bn_final<<<1, 256, 0, stream>>>(part, gg[2], bbv[2], ss2);

  // pool
  hipMemsetAsync(pool, 0, (size_t)NG * 128 * 4, stream);
  k_pool<<<(NN + 255) / 256, 128, 0, stream>>>(hb2, batch, pool);
  k_final<<<NG, 128, 0, stream>>>(pool, batch, ss2, (float*)d_out);
}